// Round 1
// baseline (454.717 us; speedup 1.0000x reference)
//
#include <hip/hip_runtime.h>

// Problem constants
#define EMB 1024
#define NH 16
#define HD 64
#define SEQ 2048
#define BB 4

typedef __attribute__((ext_vector_type(8))) short bf8;   // 8 bf16 (4 VGPRs), MFMA A/B frag
typedef __attribute__((ext_vector_type(4))) float f4;    // MFMA C/D frag

#define MFMA16(a, b, c) __builtin_amdgcn_mfma_f32_16x16x32_bf16((a), (b), (c), 0, 0, 0)

// global -> LDS direct copy, 16B per lane. LDS dest must be wave-uniform base + lane*16.
#define GLL16(g, l)                                                     \
  __builtin_amdgcn_global_load_lds(                                     \
      (__attribute__((address_space(1))) void*)(g),                     \
      (__attribute__((address_space(3))) void*)(l), 16, 0, 0)

__device__ inline unsigned short f2bf(float f) {
  union { float f; unsigned u; } v; v.f = f;
  unsigned u = v.u;
  u += 0x7fffu + ((u >> 16) & 1u);   // round-to-nearest-even
  return (unsigned short)(u >> 16);
}

// ---------------- fp32 -> bf16 convert (memory-bound) ----------------
__global__ void cvt_f32_bf16(const float* __restrict__ in,
                             unsigned short* __restrict__ out, int n4) {
  int i = blockIdx.x * blockDim.x + threadIdx.x;
  if (i < n4) {
    float4 f = ((const float4*)in)[i];
    ushort4 o;
    o.x = f2bf(f.x); o.y = f2bf(f.y); o.z = f2bf(f.z); o.w = f2bf(f.w);
    ((ushort4*)out)[i] = o;
  }
}

// ---------------- BT GEMM: C[M,N] = A[M,K] * B[N,K]^T ----------------
// 128x128 tile, BK=32, 256 threads (4 waves, each 64x64). m97 structure.
template <bool OUTF32>
__global__ __launch_bounds__(256, 2) void gemm_bt(
    const unsigned short* __restrict__ A, const unsigned short* __restrict__ B,
    void* __restrict__ Cout, const float* __restrict__ bias,
    int M, int N, int K) {
  __shared__ unsigned short la[128 * 32];
  __shared__ unsigned short lb[128 * 32];

  const int t = threadIdx.x;
  const int lane = t & 63;
  const int w = t >> 6;
  const int quad = lane >> 4;
  const int lcol = lane & 15;
  const int m0 = blockIdx.y * 128;
  const int n0 = blockIdx.x * 128;
  const int wm = (w & 1) * 64;
  const int wn = (w >> 1) * 64;

  f4 acc[4][4];
#pragma unroll
  for (int i = 0; i < 4; i++)
#pragma unroll
    for (int j = 0; j < 4; j++) acc[i][j] = (f4){0.f, 0.f, 0.f, 0.f};

  // staging: thread t covers row (c*64 + t>>2), cols (t&3)*8 .. +8, per call c
  const int srow = t >> 2;
  const int scol = (t & 3) * 8;
  const unsigned short* gA = A + (size_t)(m0 + srow) * K + scol;
  const unsigned short* gB = B + (size_t)(n0 + srow) * K + scol;
  unsigned short* lA = la + t * 8;   // byte offset t*16: wave-uniform + lane*16
  unsigned short* lB = lb + t * 8;

  for (int kt = 0; kt < K; kt += 32) {
    __syncthreads();  // protect previous iteration's LDS reads
    GLL16(gA + kt, lA);
    GLL16(gA + kt + (size_t)64 * K, lA + 64 * 32);
    GLL16(gB + kt, lB);
    GLL16(gB + kt + (size_t)64 * K, lB + 64 * 32);
    __syncthreads();  // drains vmcnt (compiler emits full waitcnt before s_barrier)

    bf8 af[4], bfr[4];
#pragma unroll
    for (int i = 0; i < 4; i++) {
      af[i]  = *(const bf8*)&la[(wm + i * 16 + lcol) * 32 + quad * 8];
      bfr[i] = *(const bf8*)&lb[(wn + i * 16 + lcol) * 32 + quad * 8];
    }
#pragma unroll
    for (int i = 0; i < 4; i++)
#pragma unroll
      for (int j = 0; j < 4; j++)
        acc[i][j] = MFMA16(af[i], bfr[j], acc[i][j]);
  }

  // epilogue: D at (row = quad*4 + r, col = lcol) within each 16x16 tile
#pragma unroll
  for (int i = 0; i < 4; i++) {
#pragma unroll
    for (int j = 0; j < 4; j++) {
#pragma unroll
      for (int r = 0; r < 4; r++) {
        int m = m0 + wm + i * 16 + quad * 4 + r;
        int n = n0 + wn + j * 16 + lcol;
        if (OUTF32) {
          float v = acc[i][j][r] + (bias ? bias[n] : 0.f);
          ((float*)Cout)[(size_t)m * N + n] = v;
        } else {
          ((unsigned short*)Cout)[(size_t)m * N + n] = f2bf(acc[i][j][r]);
        }
      }
    }
  }
}

// ---------------- flash attention ----------------
// grid: (SEQ/64, NH, BB); block 256 (4 waves). Wave w handles Q rows
// [q0 + w*16, +16). Inner loop: 64-key tiles. qkv layout [B*S][3E] bf16.
#define VTS 72  // padded LDS leading stride (breaks 128B bank alignment)

__global__ __launch_bounds__(256, 2) void attn_kernel(
    const unsigned short* __restrict__ qkv, const int* __restrict__ mask,
    unsigned short* __restrict__ outb) {
  __shared__ unsigned short kt[64 * VTS];      // K tile, row-major [key][d]
  __shared__ unsigned short vt[64 * VTS];      // V tile transposed [d][key]
  __shared__ unsigned short pt[4][16 * VTS];   // per-wave P tile [qrow][key]
  __shared__ int mlds[64];

  const int t = threadIdx.x;
  const int lane = t & 63;
  const int w = t >> 6;
  const int quad = lane >> 4;
  const int lcol = lane & 15;
  const int q0 = blockIdx.x * 64;
  const int h = blockIdx.y;
  const int b = blockIdx.z;

  const size_t rs = 3 * EMB;
  const unsigned short* qbase = qkv + (size_t)(b * SEQ) * rs + h * HD;
  const unsigned short* kbase = qbase + EMB;
  const unsigned short* vbase = qbase + 2 * EMB;

  // Q A-frags: lane holds Q[m=lcol][k=quad*8+j (+32)]
  const int qrow = q0 + w * 16 + lcol;
  bf8 qf0 = *(const bf8*)(qbase + (size_t)qrow * rs + quad * 8);
  bf8 qf1 = *(const bf8*)(qbase + (size_t)qrow * rs + 32 + quad * 8);

  f4 o[4];
  float m_i[4], l_i[4];
#pragma unroll
  for (int nb = 0; nb < 4; nb++) o[nb] = (f4){0.f, 0.f, 0.f, 0.f};
#pragma unroll
  for (int r = 0; r < 4; r++) { m_i[r] = -1e38f; l_i[r] = 0.f; }

  const int kr = t >> 2;         // staging row 0..63
  const int kc = (t & 3) * 16;   // staging col base

  for (int k0 = 0; k0 < SEQ; k0 += 64) {
    __syncthreads();  // protect previous iteration's kt/vt/mlds reads
    {
      const unsigned short* g = kbase + (size_t)(k0 + kr) * rs + kc;
      *(uint4*)&kt[kr * VTS + kc] = *(const uint4*)g;
      *(uint4*)&kt[kr * VTS + kc + 8] = *(const uint4*)(g + 8);
      const unsigned short* gv = vbase + (size_t)(k0 + kr) * rs + kc;
      unsigned short vv[16];
      *(uint4*)&vv[0] = *(const uint4*)gv;
      *(uint4*)&vv[8] = *(const uint4*)(gv + 8);
#pragma unroll
      for (int j = 0; j < 16; j++) vt[(kc + j) * VTS + kr] = vv[j];
    }
    if (t < 64) mlds[t] = mask[b * SEQ + k0 + t];
    __syncthreads();

    // S = Q K^T : 4 n-blocks of 16 keys
    f4 s[4];
#pragma unroll
    for (int nb = 0; nb < 4; nb++) {
      bf8 kf0 = *(const bf8*)&kt[(nb * 16 + lcol) * VTS + quad * 8];
      bf8 kf1 = *(const bf8*)&kt[(nb * 16 + lcol) * VTS + 32 + quad * 8];
      f4 a = (f4){0.f, 0.f, 0.f, 0.f};
      a = MFMA16(qf0, kf0, a);
      a = MFMA16(qf1, kf1, a);
      s[nb] = a;
    }

    // online softmax per q-row (row = quad*4 + r, cols = nb*16 + lcol)
    float p[4][4];
#pragma unroll
    for (int r = 0; r < 4; r++) {
      float sm = -1e38f;
#pragma unroll
      for (int nb = 0; nb < 4; nb++) {
        float sv = s[nb][r] * 0.125f;  // 1/sqrt(64)
        sv = mlds[nb * 16 + lcol] ? sv : -1e9f;
        p[r][nb] = sv;
        sm = fmaxf(sm, sv);
      }
      sm = fmaxf(sm, __shfl_xor(sm, 1));
      sm = fmaxf(sm, __shfl_xor(sm, 2));
      sm = fmaxf(sm, __shfl_xor(sm, 4));
      sm = fmaxf(sm, __shfl_xor(sm, 8));
      float mnew = fmaxf(m_i[r], sm);
      float alpha = __expf(m_i[r] - mnew);
      float rsum = 0.f;
#pragma unroll
      for (int nb = 0; nb < 4; nb++) {
        float pv = __expf(p[r][nb] - mnew);
        p[r][nb] = pv;
        rsum += pv;
      }
      rsum += __shfl_xor(rsum, 1);
      rsum += __shfl_xor(rsum, 2);
      rsum += __shfl_xor(rsum, 4);
      rsum += __shfl_xor(rsum, 8);
      l_i[r] = l_i[r] * alpha + rsum;
      m_i[r] = mnew;
#pragma unroll
      for (int nb = 0; nb < 4; nb++) {
        o[nb][r] *= alpha;
        pt[w][(quad * 4 + r) * VTS + nb * 16 + lcol] = f2bf(p[r][nb]);
      }
    }
    // per-wave LDS write->read; enforce visibility ordering
    asm volatile("s_waitcnt lgkmcnt(0)" ::: "memory");

    bf8 pa0 = *(const bf8*)&pt[w][lcol * VTS + quad * 8];
    bf8 pa1 = *(const bf8*)&pt[w][lcol * VTS + 32 + quad * 8];
#pragma unroll
    for (int nb = 0; nb < 4; nb++) {
      bf8 vf0 = *(const bf8*)&vt[(nb * 16 + lcol) * VTS + quad * 8];
      bf8 vf1 = *(const bf8*)&vt[(nb * 16 + lcol) * VTS + 32 + quad * 8];
      o[nb] = MFMA16(pa0, vf0, o[nb]);
      o[nb] = MFMA16(pa1, vf1, o[nb]);
    }
  }

  float inv[4];
#pragma unroll
  for (int r = 0; r < 4; r++) inv[r] = 1.f / l_i[r];
#pragma unroll
  for (int nb = 0; nb < 4; nb++) {
#pragma unroll
    for (int r = 0; r < 4; r++) {
      int srow = q0 + w * 16 + quad * 4 + r;
      outb[(size_t)(b * SEQ + srow) * EMB + h * HD + nb * 16 + lcol] =
          f2bf(o[nb][r] * inv[r]);
    }
  }
}

extern "C" void kernel_launch(void* const* d_in, const int* in_sizes, int n_in,
                              void* d_out, int out_size, void* d_ws, size_t ws_size,
                              hipStream_t stream) {
  const float* x     = (const float*)d_in[0];
  const float* w_qkv = (const float*)d_in[1];
  const float* w_out = (const float*)d_in[2];
  const float* b_out = (const float*)d_in[3];
  const int*   mask  = (const int*)d_in[4];

  char* ws = (char*)d_ws;
  unsigned short* xb    = (unsigned short*)(ws + 0);          // 16 MB [8192][1024]
  unsigned short* wqkvb = (unsigned short*)(ws + 16777216);   //  6 MB [3072][1024]
  unsigned short* woutb = (unsigned short*)(ws + 23068672);   //  2 MB [1024][1024]
  unsigned short* qkvb  = (unsigned short*)(ws + 25165824);   // 48 MB [8192][3072]
  unsigned short* attnb = (unsigned short*)(ws + 75497472);   // 16 MB [8192][1024]

  cvt_f32_bf16<<<8192, 256, 0, stream>>>(x, xb, 8388608 / 4);
  cvt_f32_bf16<<<3072, 256, 0, stream>>>(w_qkv, wqkvb, 3145728 / 4);
  cvt_f32_bf16<<<1024, 256, 0, stream>>>(w_out, woutb, 1048576 / 4);

  // QKV projection: [8192,1024] x [3072,1024]^T -> [8192,3072] bf16
  gemm_bt<false><<<dim3(24, 64), 256, 0, stream>>>(
      xb, wqkvb, (void*)qkvb, nullptr, 8192, 3072, 1024);

  // attention: grid (S/64, H, B)
  attn_kernel<<<dim3(32, 16, 4), 256, 0, stream>>>(qkvb, mask, attnb);

  // out projection + bias: [8192,1024] x [1024,1024]^T -> fp32 d_out
  gemm_bt<true><<<dim3(8, 64), 256, 0, stream>>>(
      attnb, woutb, d_out, b_out, 8192, 1024, 1024);
}

// Round 2
// 364.684 us; speedup vs baseline: 1.2469x; 1.2469x over previous
//
#include <hip/hip_runtime.h>

// Problem constants
#define EMB 1024
#define NH 16
#define HD 64
#define SEQ 2048
#define BB 4

typedef __attribute__((ext_vector_type(8))) short bf8;   // 8 bf16 (4 VGPRs)
typedef __attribute__((ext_vector_type(4))) short bf4;   // 4 bf16 (2 VGPRs)
typedef __attribute__((ext_vector_type(4))) float f4;    // MFMA C/D frag

#define MFMA16(a, b, c) __builtin_amdgcn_mfma_f32_16x16x32_bf16((a), (b), (c), 0, 0, 0)

// PV MFMA: 16x16x16 bf16. Prefer the _1k builtin; fall back to zero-padded K=32.
#if defined(__has_builtin)
#if __has_builtin(__builtin_amdgcn_mfma_f32_16x16x16_bf16_1k)
#define HAVE_MFMA16X16 1
#endif
#endif

__device__ inline f4 pv_mfma(bf4 a, bf4 b, f4 c) {
#ifdef HAVE_MFMA16X16
  return __builtin_amdgcn_mfma_f32_16x16x16_bf16_1k(a, b, c, 0, 0, 0);
#else
  // zero-pad to K=32: place the 4 valid k at j=0..3 of each quad's 8; B upper 4 = 0
  bf8 av, bv;
  *(bf4*)&av = a;  ((int*)&av)[2] = 0; ((int*)&av)[3] = 0;
  *(bf4*)&bv = b;  ((int*)&bv)[2] = 0; ((int*)&bv)[3] = 0;
  return __builtin_amdgcn_mfma_f32_16x16x32_bf16(av, bv, c, 0, 0, 0);
#endif
}

// global -> LDS direct copy, 16B per lane (wave-uniform base + lane*16).
#define GLL16(g, l)                                                     \
  __builtin_amdgcn_global_load_lds(                                     \
      (__attribute__((address_space(1))) void*)(g),                     \
      (__attribute__((address_space(3))) void*)(l), 16, 0, 0)

__device__ inline unsigned short f2bf(float f) {
  union { float f; unsigned u; } v; v.f = f;
  unsigned u = v.u;
  u += 0x7fffu + ((u >> 16) & 1u);   // RNE
  return (unsigned short)(u >> 16);
}

// pack two fp32 -> bf16x2 dword, round-half-up (inputs are probabilities, no NaN/Inf)
__device__ inline unsigned pkbf(float a, float b) {
  union { float f; unsigned u; } ua, ub; ua.f = a; ub.f = b;
  return ((ua.u + 0x8000u) >> 16) | ((ub.u + 0x8000u) & 0xFFFF0000u);
}

// ---------------- fp32 -> bf16 convert (memory-bound) ----------------
__global__ void cvt_f32_bf16(const float* __restrict__ in,
                             unsigned short* __restrict__ out, int n4) {
  int i = blockIdx.x * blockDim.x + threadIdx.x;
  if (i < n4) {
    float4 f = ((const float4*)in)[i];
    ushort4 o;
    o.x = f2bf(f.x); o.y = f2bf(f.y); o.z = f2bf(f.z); o.w = f2bf(f.w);
    ((ushort4*)out)[i] = o;
  }
}

// ---------------- BT GEMM: C[M,N] = A[M,K] * B[N,K]^T ----------------
// 128x128 tile, BK=32, 256 threads (4 waves). m97 structure.
// Columns n >= nsplit are stored TRANSPOSED into vtb[(b*1024 + (n-nsplit))][2048]
// (b = m>>11, s = m&2047) — fuses the V-transpose into the QKV GEMM epilogue
// and makes those stores vectorizable (consecutive m = consecutive s).
template <bool OUTF32>
__global__ __launch_bounds__(256, 2) void gemm_bt(
    const unsigned short* __restrict__ A, const unsigned short* __restrict__ B,
    void* __restrict__ Cout, const float* __restrict__ bias,
    unsigned short* __restrict__ vtb,
    int M, int N, int K, int ldC, int nsplit) {
  __shared__ unsigned short la[128 * 32];
  __shared__ unsigned short lb[128 * 32];

  const int t = threadIdx.x;
  const int lane = t & 63;
  const int w = t >> 6;
  const int quad = lane >> 4;
  const int lcol = lane & 15;
  const int m0 = blockIdx.y * 128;
  const int n0 = blockIdx.x * 128;
  const int wm = (w & 1) * 64;
  const int wn = (w >> 1) * 64;

  f4 acc[4][4];
#pragma unroll
  for (int i = 0; i < 4; i++)
#pragma unroll
    for (int j = 0; j < 4; j++) acc[i][j] = (f4){0.f, 0.f, 0.f, 0.f};

  const int srow = t >> 2;
  const int scol = (t & 3) * 8;
  const unsigned short* gA = A + (size_t)(m0 + srow) * K + scol;
  const unsigned short* gB = B + (size_t)(n0 + srow) * K + scol;
  unsigned short* lA = la + t * 8;
  unsigned short* lB = lb + t * 8;

  for (int kt = 0; kt < K; kt += 32) {
    __syncthreads();
    GLL16(gA + kt, lA);
    GLL16(gA + kt + (size_t)64 * K, lA + 64 * 32);
    GLL16(gB + kt, lB);
    GLL16(gB + kt + (size_t)64 * K, lB + 64 * 32);
    __syncthreads();

    bf8 af[4], bfr[4];
#pragma unroll
    for (int i = 0; i < 4; i++) {
      af[i]  = *(const bf8*)&la[(wm + i * 16 + lcol) * 32 + quad * 8];
      bfr[i] = *(const bf8*)&lb[(wn + i * 16 + lcol) * 32 + quad * 8];
    }
#pragma unroll
    for (int i = 0; i < 4; i++)
#pragma unroll
      for (int j = 0; j < 4; j++)
        acc[i][j] = MFMA16(af[i], bfr[j], acc[i][j]);
  }

  if (!OUTF32 && n0 >= nsplit) {
    // transposed V store path
#pragma unroll
    for (int i = 0; i < 4; i++) {
#pragma unroll
      for (int j = 0; j < 4; j++) {
        int f = n0 + wn + j * 16 + lcol - nsplit;      // 0..1023 = h*64+d
        int mg = m0 + wm + i * 16 + quad * 4;          // flat b*2048+s, s%4==0
        int bb = mg >> 11, ss = mg & 2047;
        ushort4 pk;
        pk.x = f2bf(acc[i][j][0]); pk.y = f2bf(acc[i][j][1]);
        pk.z = f2bf(acc[i][j][2]); pk.w = f2bf(acc[i][j][3]);
        *(ushort4*)&vtb[((size_t)(bb * 1024 + f)) * 2048 + ss] = pk;
      }
    }
  } else {
#pragma unroll
    for (int i = 0; i < 4; i++) {
#pragma unroll
      for (int j = 0; j < 4; j++) {
#pragma unroll
        for (int r = 0; r < 4; r++) {
          int m = m0 + wm + i * 16 + quad * 4 + r;
          int n = n0 + wn + j * 16 + lcol;
          if (OUTF32) {
            float v = acc[i][j][r] + (bias ? bias[n] : 0.f);
            ((float*)Cout)[(size_t)m * ldC + n] = v;
          } else {
            ((unsigned short*)Cout)[(size_t)m * ldC + n] = f2bf(acc[i][j][r]);
          }
        }
      }
    }
  }
}

// ---------------- flash attention, S^T orientation ----------------
// grid: (SEQ/64, NH, BB); block 256 (4 waves). Wave w: q in [q0+w*16, +16).
// S^T = K Q^T  -> lane owns ONE q-row (q=lcol), keys 16kb+4quad+r.
// Softmax: in-register + 2 shuffles. P stays in registers (B-frag of 16x16x16).
// V^T pre-transposed in global (vtg [(b*16+h)*64 + d][SEQ]).
#define LSTR 72  // padded LDS leading stride (shorts)
#define SCALE_LOG2E 0.1803368801111244f  // (1/8) * log2(e)

__global__ __launch_bounds__(256, 4) void attn_kernel(
    const unsigned short* __restrict__ qk, const unsigned short* __restrict__ vtg,
    const int* __restrict__ mask, unsigned short* __restrict__ outb) {
  __shared__ unsigned short kt[64 * LSTR];      // K tile [key][d]
  __shared__ unsigned short vt[64 * LSTR];      // V^T tile [d][key]
  __shared__ __align__(16) float bt[64];        // mask bias per key (log2 domain)

  const int t = threadIdx.x;
  const int lane = t & 63;
  const int w = t >> 6;
  const int quad = lane >> 4;
  const int lcol = lane & 15;
  const int q0 = blockIdx.x * 64;
  const int h = blockIdx.y;
  const int b = blockIdx.z;

  const unsigned short* qbase = qk + (size_t)(b * SEQ) * 2048 + h * HD;
  const unsigned short* kbase = qbase + 1024;
  const unsigned short* vbase = vtg + (size_t)((b * 16 + h) * 64) * SEQ;

  // Q B-frag: lane holds Q[n=q=lcol][k=d=quad*8+j (+32)]
  const int qrow = q0 + w * 16 + lcol;
  const bf8 qf0 = *(const bf8*)(qbase + (size_t)qrow * 2048 + quad * 8);
  const bf8 qf1 = *(const bf8*)(qbase + (size_t)qrow * 2048 + 32 + quad * 8);

  f4 o[4];   // O^T frags: lane holds O^T[d=16db+4quad+r][q=lcol]
#pragma unroll
  for (int db = 0; db < 4; db++) o[db] = (f4){0.f, 0.f, 0.f, 0.f};
  float m_i = -1e30f, l_i = 0.f;

  const int sr = t >> 2;         // staging row 0..63
  const int sc = (t & 3) * 16;   // staging col base (shorts)
  const unsigned short* gk = kbase + (size_t)sr * 2048 + sc;  // + key*2048
  const unsigned short* gv = vbase + (size_t)sr * SEQ + sc;   // + key

  // prefetch tile 0 into registers
  uint4 pk0 = *(const uint4*)gk;
  uint4 pk1 = *(const uint4*)(gk + 8);
  uint4 pv0 = *(const uint4*)gv;
  uint4 pv1 = *(const uint4*)(gv + 8);
  int pmv = (t < 64) ? mask[b * SEQ + t] : 0;

  for (int k0 = 0; k0 < SEQ; k0 += 64) {
    __syncthreads();  // previous tile's LDS reads done
    *(uint4*)&kt[sr * LSTR + sc] = pk0;
    *(uint4*)&kt[sr * LSTR + sc + 8] = pk1;
    *(uint4*)&vt[sr * LSTR + sc] = pv0;
    *(uint4*)&vt[sr * LSTR + sc + 8] = pv1;
    if (t < 64) bt[t] = pmv ? 0.f : -1e30f;
    __syncthreads();

    // prefetch next tile (overlaps with compute below)
    {
      int kn = (k0 + 64 < SEQ) ? k0 + 64 : k0;
      pk0 = *(const uint4*)(gk + (size_t)kn * 2048);
      pk1 = *(const uint4*)(gk + (size_t)kn * 2048 + 8);
      pv0 = *(const uint4*)(gv + kn);
      pv1 = *(const uint4*)(gv + kn + 8);
      pmv = (t < 64) ? mask[b * SEQ + kn + t] : 0;
    }

    // S^T = K Q^T : lane gets S[q=lcol][key=16kb+4quad+r]
    f4 sT[4];
#pragma unroll
    for (int kb = 0; kb < 4; kb++) {
      bf8 kf0 = *(const bf8*)&kt[(kb * 16 + lcol) * LSTR + quad * 8];
      bf8 kf1 = *(const bf8*)&kt[(kb * 16 + lcol) * LSTR + 32 + quad * 8];
      f4 a = (f4){0.f, 0.f, 0.f, 0.f};
      a = MFMA16(kf0, qf0, a);
      a = MFMA16(kf1, qf1, a);
      sT[kb] = a;
    }

    // scale+bias (log2 domain), tile max
    float pv[4][4];
    float mt = -1e30f;
#pragma unroll
    for (int kb = 0; kb < 4; kb++) {
      float4 bb = *(const float4*)&bt[kb * 16 + quad * 4];
      pv[kb][0] = fmaf(sT[kb][0], SCALE_LOG2E, bb.x);
      pv[kb][1] = fmaf(sT[kb][1], SCALE_LOG2E, bb.y);
      pv[kb][2] = fmaf(sT[kb][2], SCALE_LOG2E, bb.z);
      pv[kb][3] = fmaf(sT[kb][3], SCALE_LOG2E, bb.w);
#pragma unroll
      for (int r = 0; r < 4; r++) mt = fmaxf(mt, pv[kb][r]);
    }
    mt = fmaxf(mt, __shfl_xor(mt, 16));
    mt = fmaxf(mt, __shfl_xor(mt, 32));

    float mnew = fmaxf(m_i, mt);
    float alpha = exp2f(m_i - mnew);
    float rsum = 0.f;
#pragma unroll
    for (int kb = 0; kb < 4; kb++)
#pragma unroll
      for (int r = 0; r < 4; r++) {
        float e = exp2f(pv[kb][r] - mnew);
        pv[kb][r] = e;
        rsum += e;
      }
    rsum += __shfl_xor(rsum, 16);
    rsum += __shfl_xor(rsum, 32);
    l_i = l_i * alpha + rsum;
    m_i = mnew;

    // pack P in-lane: B-frag of 16x16x16 wants exactly keys 16kb+4quad+j at q=lcol
    bf4 pfrag[4];
#pragma unroll
    for (int kb = 0; kb < 4; kb++) {
      unsigned u0 = pkbf(pv[kb][0], pv[kb][1]);
      unsigned u1 = pkbf(pv[kb][2], pv[kb][3]);
      union { unsigned u[2]; bf4 s; } cv;
      cv.u[0] = u0; cv.u[1] = u1;
      pfrag[kb] = cv.s;
    }

    // rescale O
#pragma unroll
    for (int db = 0; db < 4; db++)
#pragma unroll
      for (int r = 0; r < 4; r++) o[db][r] *= alpha;

    // PV: O^T[d][q] += V^T A-frag x P B-frag
#pragma unroll
    for (int db = 0; db < 4; db++) {
#pragma unroll
      for (int kb = 0; kb < 4; kb++) {
        bf4 vf = *(const bf4*)&vt[(db * 16 + lcol) * LSTR + kb * 16 + quad * 4];
        o[db] = pv_mfma(vf, pfrag[kb], o[db]);
      }
    }
  }

  float inv = 1.f / l_i;
#pragma unroll
  for (int db = 0; db < 4; db++) {
    ushort4 pk;
    pk.x = f2bf(o[db][0] * inv);
    pk.y = f2bf(o[db][1] * inv);
    pk.z = f2bf(o[db][2] * inv);
    pk.w = f2bf(o[db][3] * inv);
    *(ushort4*)&outb[(size_t)(b * SEQ + q0 + w * 16 + lcol) * EMB + h * HD +
                     db * 16 + quad * 4] = pk;
  }
}

extern "C" void kernel_launch(void* const* d_in, const int* in_sizes, int n_in,
                              void* d_out, int out_size, void* d_ws, size_t ws_size,
                              hipStream_t stream) {
  const float* x     = (const float*)d_in[0];
  const float* w_qkv = (const float*)d_in[1];
  const float* w_out = (const float*)d_in[2];
  const float* b_out = (const float*)d_in[3];
  const int*   mask  = (const int*)d_in[4];

  char* ws = (char*)d_ws;
  unsigned short* xb    = (unsigned short*)(ws + 0);          // 16 MB [8192][1024]
  unsigned short* wqkvb = (unsigned short*)(ws + 16777216);   //  6 MB [3072][1024]
  unsigned short* woutb = (unsigned short*)(ws + 23068672);   //  2 MB [1024][1024]
  unsigned short* qkb   = (unsigned short*)(ws + 25165824);   // 32 MB [8192][2048] (Q|K)
  unsigned short* attnb = (unsigned short*)(ws + 58720256);   // 16 MB [8192][1024]
  unsigned short* vtb   = (unsigned short*)(ws + 75497472);   // 16 MB [4096][2048] V^T

  cvt_f32_bf16<<<8192, 256, 0, stream>>>(x, xb, 8388608 / 4);
  cvt_f32_bf16<<<3072, 256, 0, stream>>>(w_qkv, wqkvb, 3145728 / 4);
  cvt_f32_bf16<<<1024, 256, 0, stream>>>(w_out, woutb, 1048576 / 4);

  // QKV projection: Q,K -> qkb (ld 2048); V (n>=2048) -> vtb transposed
  gemm_bt<false><<<dim3(24, 64), 256, 0, stream>>>(
      xb, wqkvb, (void*)qkb, nullptr, vtb, 8192, 3072, 1024, 2048, 2048);

  // attention
  attn_kernel<<<dim3(32, 16, 4), 256, 0, stream>>>(qkb, vtb, mask, attnb);

  // out projection + bias -> fp32 d_out
  gemm_bt<true><<<dim3(8, 64), 256, 0, stream>>>(
      attnb, woutb, d_out, b_out, nullptr, 8192, 1024, 1024, 1024, 1 << 30);
}

// Round 3
// 345.495 us; speedup vs baseline: 1.3161x; 1.0555x over previous
//
#include <hip/hip_runtime.h>

// Problem constants
#define EMB 1024
#define NH 16
#define HD 64
#define SEQ 2048
#define BB 4

typedef __attribute__((ext_vector_type(8))) short bf8;   // 8 bf16 (4 VGPRs)
typedef __attribute__((ext_vector_type(4))) short bf4;   // 4 bf16 (2 VGPRs)
typedef __attribute__((ext_vector_type(4))) float f4;    // MFMA C/D frag

#define MFMA16(a, b, c) __builtin_amdgcn_mfma_f32_16x16x32_bf16((a), (b), (c), 0, 0, 0)

#if defined(__has_builtin)
#if __has_builtin(__builtin_amdgcn_mfma_f32_16x16x16_bf16_1k)
#define HAVE_MFMA16X16 1
#endif
#if __has_builtin(__builtin_amdgcn_exp2f)
#define EXP2F __builtin_amdgcn_exp2f
#endif
#endif
#ifndef EXP2F
#define EXP2F exp2f
#endif

__device__ inline f4 pv_mfma(bf4 a, bf4 b, f4 c) {
#ifdef HAVE_MFMA16X16
  return __builtin_amdgcn_mfma_f32_16x16x16_bf16_1k(a, b, c, 0, 0, 0);
#else
  bf8 av, bv;
  *(bf4*)&av = a;  ((int*)&av)[2] = 0; ((int*)&av)[3] = 0;
  *(bf4*)&bv = b;  ((int*)&bv)[2] = 0; ((int*)&bv)[3] = 0;
  return __builtin_amdgcn_mfma_f32_16x16x32_bf16(av, bv, c, 0, 0, 0);
#endif
}

// global -> LDS direct copy, 16B per lane (wave-uniform base + lane*16).
#define GLL16(g, l)                                                     \
  __builtin_amdgcn_global_load_lds(                                     \
      (__attribute__((address_space(1))) void*)(g),                     \
      (__attribute__((address_space(3))) void*)(l), 16, 0, 0)

__device__ inline unsigned short f2bf(float f) {
  union { float f; unsigned u; } v; v.f = f;
  unsigned u = v.u;
  u += 0x7fffu + ((u >> 16) & 1u);   // RNE
  return (unsigned short)(u >> 16);
}

// pack two fp32 -> bf16x2 dword, round-half-up (probabilities: no NaN/Inf)
__device__ inline unsigned pkbf(float a, float b) {
  union { float f; unsigned u; } ua, ub; ua.f = a; ub.f = b;
  return ((ua.u + 0x8000u) >> 16) | ((ub.u + 0x8000u) & 0xFFFF0000u);
}

// ---------------- fp32 -> bf16 convert (memory-bound) ----------------
__global__ void cvt_f32_bf16(const float* __restrict__ in,
                             unsigned short* __restrict__ out, int n4) {
  int i = blockIdx.x * blockDim.x + threadIdx.x;
  if (i < n4) {
    float4 f = ((const float4*)in)[i];
    ushort4 o;
    o.x = f2bf(f.x); o.y = f2bf(f.y); o.z = f2bf(f.z); o.w = f2bf(f.w);
    ((ushort4*)out)[i] = o;
  }
}

// ---------------- BT GEMM: C[M,N] = A[M,K] * B[N,K]^T ----------------
// 128x128 tile, BK=32, 256 threads (4 waves). m97 structure.
// Columns n >= nsplit stored TRANSPOSED into vtb[(b*1024 + (n-nsplit))][2048].
template <bool OUTF32>
__global__ __launch_bounds__(256, 2) void gemm_bt(
    const unsigned short* __restrict__ A, const unsigned short* __restrict__ B,
    void* __restrict__ Cout, const float* __restrict__ bias,
    unsigned short* __restrict__ vtb,
    int M, int N, int K, int ldC, int nsplit) {
  __shared__ unsigned short la[128 * 32];
  __shared__ unsigned short lb[128 * 32];

  const int t = threadIdx.x;
  const int lane = t & 63;
  const int w = t >> 6;
  const int quad = lane >> 4;
  const int lcol = lane & 15;
  const int m0 = blockIdx.y * 128;
  const int n0 = blockIdx.x * 128;
  const int wm = (w & 1) * 64;
  const int wn = (w >> 1) * 64;

  f4 acc[4][4];
#pragma unroll
  for (int i = 0; i < 4; i++)
#pragma unroll
    for (int j = 0; j < 4; j++) acc[i][j] = (f4){0.f, 0.f, 0.f, 0.f};

  const int srow = t >> 2;
  const int scol = (t & 3) * 8;
  const unsigned short* gA = A + (size_t)(m0 + srow) * K + scol;
  const unsigned short* gB = B + (size_t)(n0 + srow) * K + scol;
  unsigned short* lA = la + t * 8;
  unsigned short* lB = lb + t * 8;

  for (int kt = 0; kt < K; kt += 32) {
    __syncthreads();
    GLL16(gA + kt, lA);
    GLL16(gA + kt + (size_t)64 * K, lA + 64 * 32);
    GLL16(gB + kt, lB);
    GLL16(gB + kt + (size_t)64 * K, lB + 64 * 32);
    __syncthreads();

    bf8 af[4], bfr[4];
#pragma unroll
    for (int i = 0; i < 4; i++) {
      af[i]  = *(const bf8*)&la[(wm + i * 16 + lcol) * 32 + quad * 8];
      bfr[i] = *(const bf8*)&lb[(wn + i * 16 + lcol) * 32 + quad * 8];
    }
#pragma unroll
    for (int i = 0; i < 4; i++)
#pragma unroll
      for (int j = 0; j < 4; j++)
        acc[i][j] = MFMA16(af[i], bfr[j], acc[i][j]);
  }

  if (!OUTF32 && n0 >= nsplit) {
#pragma unroll
    for (int i = 0; i < 4; i++) {
#pragma unroll
      for (int j = 0; j < 4; j++) {
        int f = n0 + wn + j * 16 + lcol - nsplit;      // 0..1023 = h*64+d
        int mg = m0 + wm + i * 16 + quad * 4;          // flat b*2048+s, s%4==0
        int bb = mg >> 11, ss = mg & 2047;
        ushort4 pk;
        pk.x = f2bf(acc[i][j][0]); pk.y = f2bf(acc[i][j][1]);
        pk.z = f2bf(acc[i][j][2]); pk.w = f2bf(acc[i][j][3]);
        *(ushort4*)&vtb[((size_t)(bb * 1024 + f)) * 2048 + ss] = pk;
      }
    }
  } else {
#pragma unroll
    for (int i = 0; i < 4; i++) {
#pragma unroll
      for (int j = 0; j < 4; j++) {
#pragma unroll
        for (int r = 0; r < 4; r++) {
          int m = m0 + wm + i * 16 + quad * 4 + r;
          int n = n0 + wn + j * 16 + lcol;
          if (OUTF32) {
            float v = acc[i][j][r] + (bias ? bias[n] : 0.f);
            ((float*)Cout)[(size_t)m * ldC + n] = v;
          } else {
            ((unsigned short*)Cout)[(size_t)m * ldC + n] = f2bf(acc[i][j][r]);
          }
        }
      }
    }
  }
}

// ---------------- flash attention, S^T orientation ----------------
// grid: (SEQ/64, NH, BB); block 256 (4 waves). Wave w: q in [q0+w*16, +16).
// S^T = K Q^T -> lane owns ONE q-row (q=lcol). P stays in registers.
// K/V tiles staged via global_load_lds with XOR chunk swizzle:
//   LDS[row][chunk c] holds logical chunk c ^ (row&7)   (chunk = 8 shorts = 16B)
// so GLL16's linear lane*16 writes are conflict-free AND compute reads spread
// across banks. The swizzle is applied on the GLOBAL source address.
#define SCALE_LOG2E 0.1803368801111244f  // (1/8) * log2(e)

__global__ __launch_bounds__(256, 6) void attn_kernel(
    const unsigned short* __restrict__ qk, const unsigned short* __restrict__ vtg,
    const int* __restrict__ mask, unsigned short* __restrict__ outb) {
  __shared__ unsigned short kt[64 * 64];        // K tile [key][d], swizzled
  __shared__ unsigned short vt[64 * 64];        // V^T tile [d][key], swizzled
  __shared__ __align__(16) float bt[64];        // mask bias per key (log2 domain)

  const int t = threadIdx.x;
  const int lane = t & 63;
  const int w = t >> 6;
  const int quad = lane >> 4;
  const int lcol = lane & 15;
  const int lx = lcol & 7;                      // read-side swizzle key
  const int q0 = blockIdx.x * 64;
  const int h = blockIdx.y;
  const int b = blockIdx.z;

  const unsigned short* qbase = qk + (size_t)(b * SEQ) * 2048 + h * HD;
  const unsigned short* kbase = qbase + 1024;
  const unsigned short* vbase = vtg + (size_t)((b * 16 + h) * 64) * SEQ;

  // Q B-frag: lane holds Q[n=q=lcol][k=d=quad*8+j (+32)]
  const int qrow = q0 + w * 16 + lcol;
  const bf8 qf0 = *(const bf8*)(qbase + (size_t)qrow * 2048 + quad * 8);
  const bf8 qf1 = *(const bf8*)(qbase + (size_t)qrow * 2048 + 32 + quad * 8);

  f4 o[4];   // O^T frags: lane holds O^T[d=16db+4quad+r][q=lcol]
#pragma unroll
  for (int db = 0; db < 4; db++) o[db] = (f4){0.f, 0.f, 0.f, 0.f};
  float m_i = -1e30f, l_i = 0.f;

  // staging: thread t covers row sr (+32 on sweep 1), swizzled chunk sc
  const int sr = t >> 3;                        // 0..31
  const int sc = ((t & 7) ^ (sr & 7)) * 8;      // global chunk to fetch (shorts)
  const unsigned short* gk = kbase + (size_t)sr * 2048 + sc;  // + k*2048
  const unsigned short* gv = vbase + (size_t)sr * SEQ + sc;   // + key
  unsigned short* lk = kt + t * 8;              // lane*16B, wave-uniform base
  unsigned short* lv = vt + t * 8;

  int pmv = (t < 64) ? mask[b * SEQ + t] : 0;

  for (int k0 = 0; k0 < SEQ; k0 += 64) {
    __syncthreads();  // previous tile's LDS reads done
    GLL16(gk + (size_t)k0 * 2048, lk);
    GLL16(gk + (size_t)(k0 + 32) * 2048, lk + 2048);
    GLL16(gv + k0, lv);
    GLL16(gv + k0 + 32 * SEQ, lv + 2048);
    if (t < 64) bt[t] = pmv ? 0.f : -1e30f;
    __syncthreads();  // drains vmcnt+lgkm (compiler emits full waitcnt)

    // prefetch next tile's mask value (overlaps compute)
    {
      int kn = (k0 + 64 < SEQ) ? k0 + 64 : 0;
      pmv = (t < 64) ? mask[b * SEQ + kn + t] : 0;
    }

    // S^T = K Q^T : lane gets S[q=lcol][key=16kb+4quad+r]
    f4 sT[4];
#pragma unroll
    for (int kb = 0; kb < 4; kb++) {
      const unsigned short* krow = kt + (kb * 16 + lcol) * 64;
      bf8 kf0 = *(const bf8*)&krow[(quad ^ lx) * 8];
      bf8 kf1 = *(const bf8*)&krow[((4 + quad) ^ lx) * 8];
      f4 a = (f4){0.f, 0.f, 0.f, 0.f};
      a = MFMA16(kf0, qf0, a);
      a = MFMA16(kf1, qf1, a);
      sT[kb] = a;
    }

    // scale+bias (log2 domain), tile max
    float pv[4][4];
    float mt = -1e30f;
#pragma unroll
    for (int kb = 0; kb < 4; kb++) {
      float4 bb = *(const float4*)&bt[kb * 16 + quad * 4];
      pv[kb][0] = fmaf(sT[kb][0], SCALE_LOG2E, bb.x);
      pv[kb][1] = fmaf(sT[kb][1], SCALE_LOG2E, bb.y);
      pv[kb][2] = fmaf(sT[kb][2], SCALE_LOG2E, bb.z);
      pv[kb][3] = fmaf(sT[kb][3], SCALE_LOG2E, bb.w);
#pragma unroll
      for (int r = 0; r < 4; r++) mt = fmaxf(mt, pv[kb][r]);
    }
    mt = fmaxf(mt, __shfl_xor(mt, 16));
    mt = fmaxf(mt, __shfl_xor(mt, 32));

    float mnew = fmaxf(m_i, mt);
    // rescale only when some lane's running max moved (wave-uniform branch)
    if (__any(mnew > m_i)) {
      float alpha = EXP2F(m_i - mnew);
      l_i *= alpha;
#pragma unroll
      for (int db = 0; db < 4; db++)
#pragma unroll
        for (int r = 0; r < 4; r++) o[db][r] *= alpha;
      m_i = mnew;
    }

    float rsum = 0.f;
#pragma unroll
    for (int kb = 0; kb < 4; kb++)
#pragma unroll
      for (int r = 0; r < 4; r++) {
        float e = EXP2F(pv[kb][r] - m_i);
        pv[kb][r] = e;
        rsum += e;
      }
    rsum += __shfl_xor(rsum, 16);
    rsum += __shfl_xor(rsum, 32);
    l_i += rsum;

    // pack P in-lane: B-frag of 16x16x16 = keys 16kb+4quad+j at q=lcol
    bf4 pfrag[4];
#pragma unroll
    for (int kb = 0; kb < 4; kb++) {
      union { unsigned u[2]; bf4 s; } cv;
      cv.u[0] = pkbf(pv[kb][0], pv[kb][1]);
      cv.u[1] = pkbf(pv[kb][2], pv[kb][3]);
      pfrag[kb] = cv.s;
    }

    // PV: O^T[d][q] += V^T A-frag x P B-frag (swizzled vt read)
#pragma unroll
    for (int db = 0; db < 4; db++) {
      const unsigned short* vrow = vt + (db * 16 + lcol) * 64;
#pragma unroll
      for (int kb = 0; kb < 4; kb++) {
        bf4 vf = *(const bf4*)&vrow[(((kb << 1) | (quad >> 1)) ^ lx) * 8 +
                                    (quad & 1) * 4];
        o[db] = pv_mfma(vf, pfrag[kb], o[db]);
      }
    }
  }

  float inv = 1.f / l_i;
#pragma unroll
  for (int db = 0; db < 4; db++) {
    ushort4 pk;
    pk.x = f2bf(o[db][0] * inv);
    pk.y = f2bf(o[db][1] * inv);
    pk.z = f2bf(o[db][2] * inv);
    pk.w = f2bf(o[db][3] * inv);
    *(ushort4*)&outb[(size_t)(b * SEQ + q0 + w * 16 + lcol) * EMB + h * HD +
                     db * 16 + quad * 4] = pk;
  }
}

extern "C" void kernel_launch(void* const* d_in, const int* in_sizes, int n_in,
                              void* d_out, int out_size, void* d_ws, size_t ws_size,
                              hipStream_t stream) {
  const float* x     = (const float*)d_in[0];
  const float* w_qkv = (const float*)d_in[1];
  const float* w_out = (const float*)d_in[2];
  const float* b_out = (const float*)d_in[3];
  const int*   mask  = (const int*)d_in[4];

  char* ws = (char*)d_ws;
  unsigned short* xb    = (unsigned short*)(ws + 0);          // 16 MB [8192][1024]
  unsigned short* wqkvb = (unsigned short*)(ws + 16777216);   //  6 MB [3072][1024]
  unsigned short* woutb = (unsigned short*)(ws + 23068672);   //  2 MB [1024][1024]
  unsigned short* qkb   = (unsigned short*)(ws + 25165824);   // 32 MB [8192][2048] (Q|K)
  unsigned short* attnb = (unsigned short*)(ws + 58720256);   // 16 MB [8192][1024]
  unsigned short* vtb   = (unsigned short*)(ws + 75497472);   // 16 MB [4096][2048] V^T

  cvt_f32_bf16<<<8192, 256, 0, stream>>>(x, xb, 8388608 / 4);
  cvt_f32_bf16<<<3072, 256, 0, stream>>>(w_qkv, wqkvb, 3145728 / 4);
  cvt_f32_bf16<<<1024, 256, 0, stream>>>(w_out, woutb, 1048576 / 4);

  // QKV projection: Q,K -> qkb (ld 2048); V (n>=2048) -> vtb transposed
  gemm_bt<false><<<dim3(24, 64), 256, 0, stream>>>(
      xb, wqkvb, (void*)qkb, nullptr, vtb, 8192, 3072, 1024, 2048, 2048);

  // attention
  attn_kernel<<<dim3(32, 16, 4), 256, 0, stream>>>(qkb, vtb, mask, attnb);

  // out projection + bias -> fp32 d_out
  gemm_bt<true><<<dim3(8, 64), 256, 0, stream>>>(
      attnb, woutb, d_out, b_out, nullptr, 8192, 1024, 1024, 1024, 1 << 30);
}